// Round 5
// baseline (499.033 us; speedup 1.0000x reference)
//
#include <hip/hip_runtime.h>
#include <math.h>

#define BB 128
#define NN 128
#define DIN 1024
#define H1 256
#define DOUT 32
#define KCL 8
#define NPTS 128
#define MROWS (BB*NN)   // 16384
#define CSTR 130        // centsT row stride (words)
#define RSTR 132        // cost row stride (words, 16B aligned)
#define DEADKEY 0xFFFFFFFF00000000ull

__device__ __forceinline__ float gelu_exact(float v) {
    return 0.5f * v * (1.0f + erff(v * 0.70710678118654752f));
}

__device__ __forceinline__ unsigned long long mkkey(float v, int r, int j) {
    return ((unsigned long long)__float_as_uint(v) << 32) | (unsigned)((r << 7) | j);
}

// u32 min via DPP (costs are >=0 floats: IEEE order == unsigned bit order)
template<int CTRL, int RMASK>
__device__ __forceinline__ unsigned dpp_umin_step(unsigned v) {
    unsigned t = (unsigned)__builtin_amdgcn_update_dpp((int)v, (int)v, CTRL, RMASK, 0xf, false);
    return t < v ? t : v;
}
__device__ __forceinline__ unsigned wave_umin_bcast(unsigned v) {
    v = dpp_umin_step<0x111, 0xf>(v);
    v = dpp_umin_step<0x112, 0xf>(v);
    v = dpp_umin_step<0x114, 0xf>(v);
    v = dpp_umin_step<0x118, 0xf>(v);
    v = dpp_umin_step<0x142, 0xa>(v);
    v = dpp_umin_step<0x143, 0xc>(v);
    return (unsigned)__builtin_amdgcn_readlane((int)v, 63);
}
// lane31 = min(lanes0..31), lane63 = min(lanes32..63)
__device__ __forceinline__ unsigned half_umin(unsigned v) {
    v = dpp_umin_step<0x111, 0xf>(v);
    v = dpp_umin_step<0x112, 0xf>(v);
    v = dpp_umin_step<0x114, 0xf>(v);
    v = dpp_umin_step<0x118, 0xf>(v);
    v = dpp_umin_step<0x142, 0xa>(v);
    return v;
}

// ---------------- GEMM1: h = gelu(x) @ W1 + b1 ; 128x64 tile, 8x4 acc, BK=32 ----------------
__global__ __launch_bounds__(256) void mlp1_kernel(const float* __restrict__ x,
                                                   const float* __restrict__ W1,
                                                   const float* __restrict__ b1,
                                                   float* __restrict__ h) {
    __shared__ float As[32][132];  // [k][m]
    __shared__ float Bs[32][68];   // [k][n]
    const int bm = blockIdx.x;     // 128 row-tiles of 128
    const int bn = blockIdx.y;     // 4 col-tiles of 64
    const int tid = threadIdx.x;
    const int tx = tid & 15, ty = tid >> 4;

    float acc[8][4];
#pragma unroll
    for (int i = 0; i < 8; ++i)
#pragma unroll
        for (int j = 0; j < 4; ++j) acc[i][j] = 0.f;

    const int ar0 = tid >> 2;          // 0..63 -> rows ar0, ar0+64
    const int aq = (tid & 3) * 4;      // 0,4,8,12
    const int bk = tid >> 4;           // 0..15
    const int bc4 = (tid & 15) * 4;

    const float* xb = x + (size_t)(bm * 128) * DIN;
    const float* wb = W1 + bn * 64;

    for (int kt = 0; kt < DIN; kt += 32) {
        float4 a00 = *(const float4*)(xb + (size_t)ar0 * DIN + kt + aq);
        float4 a01 = *(const float4*)(xb + (size_t)ar0 * DIN + kt + 16 + aq);
        float4 a10 = *(const float4*)(xb + (size_t)(ar0 + 64) * DIN + kt + aq);
        float4 a11 = *(const float4*)(xb + (size_t)(ar0 + 64) * DIN + kt + 16 + aq);
        float4 w0 = *(const float4*)(wb + (size_t)(kt + bk) * H1 + bc4);
        float4 w1 = *(const float4*)(wb + (size_t)(kt + 16 + bk) * H1 + bc4);
        __syncthreads();
        As[aq + 0][ar0] = gelu_exact(a00.x);
        As[aq + 1][ar0] = gelu_exact(a00.y);
        As[aq + 2][ar0] = gelu_exact(a00.z);
        As[aq + 3][ar0] = gelu_exact(a00.w);
        As[16 + aq + 0][ar0] = gelu_exact(a01.x);
        As[16 + aq + 1][ar0] = gelu_exact(a01.y);
        As[16 + aq + 2][ar0] = gelu_exact(a01.z);
        As[16 + aq + 3][ar0] = gelu_exact(a01.w);
        As[aq + 0][ar0 + 64] = gelu_exact(a10.x);
        As[aq + 1][ar0 + 64] = gelu_exact(a10.y);
        As[aq + 2][ar0 + 64] = gelu_exact(a10.z);
        As[aq + 3][ar0 + 64] = gelu_exact(a10.w);
        As[16 + aq + 0][ar0 + 64] = gelu_exact(a11.x);
        As[16 + aq + 1][ar0 + 64] = gelu_exact(a11.y);
        As[16 + aq + 2][ar0 + 64] = gelu_exact(a11.z);
        As[16 + aq + 3][ar0 + 64] = gelu_exact(a11.w);
        *(float4*)&Bs[bk][bc4] = w0;
        *(float4*)&Bs[16 + bk][bc4] = w1;
        __syncthreads();
#pragma unroll
        for (int kk = 0; kk < 32; ++kk) {
            float a[8], b[4];
            *(float4*)&a[0] = *(const float4*)&As[kk][ty * 8];
            *(float4*)&a[4] = *(const float4*)&As[kk][ty * 8 + 4];
            *(float4*)&b[0] = *(const float4*)&Bs[kk][tx * 4];
#pragma unroll
            for (int i = 0; i < 8; ++i)
#pragma unroll
                for (int j = 0; j < 4; ++j)
                    acc[i][j] = fmaf(a[i], b[j], acc[i][j]);
        }
    }

    const int row = bm * 128 + ty * 8;
    const int col = bn * 64 + tx * 4;
    float4 bias = *(const float4*)(b1 + col);
#pragma unroll
    for (int i = 0; i < 8; ++i) {
        float4 o;
        o.x = acc[i][0] + bias.x;
        o.y = acc[i][1] + bias.y;
        o.z = acc[i][2] + bias.z;
        o.w = acc[i][3] + bias.w;
        *(float4*)(h + (size_t)(row + i) * H1 + col) = o;
    }
}

// ---------------- GEMM2: feats = gelu(h) @ W2 + b2 ----------------
__global__ __launch_bounds__(256) void mlp2_kernel(const float* __restrict__ h,
                                                   const float* __restrict__ W2,
                                                   const float* __restrict__ b2,
                                                   float* __restrict__ feats) {
    __shared__ float hs[16][257];
    __shared__ float w2s[H1 * DOUT];
    const int blk = blockIdx.x;
    const int tid = threadIdx.x;

    for (int i = tid; i < (H1 * DOUT) / 4; i += 256) {
        ((float4*)w2s)[i] = ((const float4*)W2)[i];
    }
    const float* hb = h + (size_t)blk * 16 * H1;
    for (int i = tid; i < (16 * H1) / 4; i += 256) {
        float4 v = ((const float4*)hb)[i];
        int r = i >> 6;
        int c = (i & 63) * 4;
        hs[r][c + 0] = gelu_exact(v.x);
        hs[r][c + 1] = gelu_exact(v.y);
        hs[r][c + 2] = gelu_exact(v.z);
        hs[r][c + 3] = gelu_exact(v.w);
    }
    __syncthreads();

    const int col = tid & 31;
    const int r0 = (tid >> 5) * 2;
    float acc0 = 0.f, acc1 = 0.f;
    for (int k = 0; k < H1; ++k) {
        float w = w2s[k * DOUT + col];
        acc0 = fmaf(hs[r0 + 0][k], w, acc0);
        acc1 = fmaf(hs[r0 + 1][k], w, acc1);
    }
    float bias = b2[col];
    const int rowg = blk * 16 + r0;
    feats[(size_t)(rowg + 0) * DOUT + col] = acc0 + bias;
    feats[(size_t)(rowg + 1) * DOUT + col] = acc1 + bias;
}

// ---------------- Ward clustering: u32-DPP argmin, prefetched centroids, alive mask ----------------
__global__ __launch_bounds__(256) void ward_kernel(const float* __restrict__ feats,
                                                   int* __restrict__ out) {
    __shared__ __align__(16) float cost[NPTS * RSTR];  // full matrix
    __shared__ float centsT[32 * CSTR];                // [d][r]
    __shared__ unsigned long long rowkey[NPTS];
    __shared__ float sqArr[NPTS];
    __shared__ float szsE[NPTS];
    __shared__ int rnk[NPTS];

    const int b = blockIdx.x;
    const int tid = threadIdx.x;
    const float* f = feats + (size_t)b * NPTS * DOUT;
    const float INF = __builtin_inff();

    // ---- init (all 4 waves) ----
    for (int i = tid; i < NPTS * DOUT; i += 256) {
        int r = i >> 5, d = i & 31;
        centsT[d * CSTR + r] = f[i];
    }
    __syncthreads();
    if (tid < NPTS) {
        float s = 0.f;
#pragma unroll
        for (int d = 0; d < 32; ++d) {
            float v = centsT[d * CSTR + tid];
            s = fmaf(v, v, s);
        }
        sqArr[tid] = s;
    }
    __syncthreads();
    {
        int ti = tid >> 4, tj = tid & 15;
        int I0 = ti * 8, J0 = tj * 8;
        float acc[8][8];
#pragma unroll
        for (int u = 0; u < 8; ++u)
#pragma unroll
            for (int v = 0; v < 8; ++v) acc[u][v] = 0.f;
        for (int d = 0; d < 32; ++d) {
            float a[8], bb[8];
#pragma unroll
            for (int u = 0; u < 8; ++u) a[u] = centsT[d * CSTR + I0 + u];
#pragma unroll
            for (int v = 0; v < 8; ++v) bb[v] = centsT[d * CSTR + J0 + v];
#pragma unroll
            for (int u = 0; u < 8; ++u)
#pragma unroll
                for (int v = 0; v < 8; ++v)
                    acc[u][v] = fmaf(a[u], bb[v], acc[u][v]);
        }
#pragma unroll
        for (int u = 0; u < 8; ++u) {
#pragma unroll
            for (int v = 0; v < 8; ++v) {
                int i = I0 + u, j = J0 + v;
                float d2 = sqArr[i] + sqArr[j] - 2.0f * acc[u][v];
                if (d2 < 0.f) d2 = 0.f;
                float w = (1.0f * 1.0f) / (1.0f + 1.0f + 1e-30f);
                cost[i * RSTR + j] = (i == j) ? INF : w * d2;
            }
        }
    }
    __syncthreads();
    if (tid < NPTS) {
        unsigned long long best = DEADKEY;
        for (int j = 0; j < NPTS; ++j) {
            float v = cost[tid * RSTR + j];
            unsigned long long k = mkkey(v, tid, j);
            if (k < best) best = k;
        }
        rowkey[tid] = best;
    }
    __syncthreads();

    if (tid >= 64) return;  // wave 0 only
    const int lane = tid;
    const int r0 = lane * 2, r1 = lane * 2 + 1;

    unsigned long long k0 = rowkey[r0], k1 = rowkey[r1];
    float q0 = sqArr[r0], q1 = sqArr[r1];
    float s0 = 1.0f, s1 = 1.0f;
    int lab0 = r0, lab1 = r1;
    unsigned long long alive0 = ~0ull, alive1 = ~0ull;  // uniform col-alive mask

    // prefetch own-row centroid pairs into registers
    float2 pref[32];
#pragma unroll
    for (int d = 0; d < 32; ++d) pref[d] = *(const float2*)&centsT[d * CSTR + r0];

    for (int it = 0; it < NPTS - KCL; ++it) {
        // P1: global argmin via u32-bits DPP min + ballot (exact flat-index tie-break)
        unsigned bv0 = (unsigned)(k0 >> 32), bv1 = (unsigned)(k1 >> 32);
        unsigned lmin = bv0 < bv1 ? bv0 : bv1;
        unsigned lflat = (bv0 <= bv1) ? (unsigned)(k0 & 0x3FFFu) : (unsigned)(k1 & 0x3FFFu);
        unsigned gmin = wave_umin_bcast(lmin);
        unsigned long long bmask = __ballot(lmin == gmin);
        int lsel = __ffsll(bmask) - 1;
        unsigned flat = (unsigned)__builtin_amdgcn_readlane((int)lflat, lsel);
        int ra = (int)(flat >> 7), ca = (int)(flat & 127u);
        const int i2 = ra < ca ? ra : ca;
        const int j2 = ra < ca ? ca : ra;

        float candi = (i2 & 1) ? s1 : s0;
        float candj = (j2 & 1) ? s1 : s0;
        float si = __int_as_float(__builtin_amdgcn_readlane(__float_as_int(candi), i2 >> 1));
        float sj = __int_as_float(__builtin_amdgcn_readlane(__float_as_int(candj), j2 >> 1));
        const float snew = si + sj;

        int arg0 = (int)(k0 & 127u), arg1 = (int)(k1 & 127u);
        bool d0 = (s0 > 0.f) && r0 != i2 && r0 != j2 && (arg0 == i2 || arg0 == j2);
        bool d1 = (s1 > 0.f) && r1 != i2 && r1 != j2 && (arg1 == i2 || arg1 == j2);
        unsigned long long m0 = __ballot(d0), m1 = __ballot(d1);

        // P3: merge centroid (lanes<32 = dim d), update scalar state
        float newc = 0.f;
        if (lane < 32) {
            float ci = centsT[lane * CSTR + i2];
            float cj = centsT[lane * CSTR + j2];
            newc = (ci * si + cj * sj) / (si + sj);
            centsT[lane * CSTR + i2] = newc;
        }
        if (lab0 == j2) lab0 = i2;
        if (lab1 == j2) lab1 = i2;
        if (r0 == i2) s0 = snew; else if (r0 == j2) { s0 = 0.f; k0 = DEADKEY; }
        if (r1 == i2) s1 = snew; else if (r1 == j2) { s1 = 0.f; k1 = DEADKEY; }
        if (j2 < 64) alive0 &= ~(1ull << j2); else alive1 &= ~(1ull << (j2 - 64));

        // broadcast merged centroid to all lanes
        float c2[32];
#pragma unroll
        for (int d = 0; d < 32; ++d)
            c2[d] = __int_as_float(__builtin_amdgcn_readlane(__float_as_int(newc), d));

        // P4: pure-VALU dots from prefetched registers (stale only for unused rows)
        float qn = 0.f, dot0 = 0.f, dot1 = 0.f;
#pragma unroll
        for (int d = 0; d < 32; ++d) {
            float cc = c2[d];
            qn = fmaf(cc, cc, qn);
            dot0 = fmaf(pref[d].x, cc, dot0);
            dot1 = fmaf(pref[d].y, cc, dot1);
        }
        if (r0 == i2) q0 = qn;
        if (r1 == i2) q1 = qn;
        bool w0 = (s0 > 0.f) && r0 != i2 && r0 != j2;
        bool w1 = (s1 > 0.f) && r1 != i2 && r1 != j2;
        float v0 = 0.f, v1 = 0.f;
        unsigned cb0 = 0xFFFFFFFFu, cb1 = 0xFFFFFFFFu;
        if (w0) {
            float d2 = q0 + qn - 2.0f * dot0;
            if (d2 < 0.f) d2 = 0.f;
            float w = (s0 * snew) / (s0 + snew + 1e-30f);
            v0 = w * d2;
            cost[r0 * RSTR + i2] = v0;
            cost[i2 * RSTR + r0] = v0;
            cb0 = __float_as_uint(v0);
            if (!d0) {
                unsigned long long nk = mkkey(v0, r0, i2);
                if (nk < k0) k0 = nk;
            }
        }
        if (w1) {
            float d2 = q1 + qn - 2.0f * dot1;
            if (d2 < 0.f) d2 = 0.f;
            float w = (s1 * snew) / (s1 + snew + 1e-30f);
            v1 = w * d2;
            cost[r1 * RSTR + i2] = v1;
            cost[i2 * RSTR + r1] = v1;
            cb1 = __float_as_uint(v1);
            if (!d1) {
                unsigned long long nk = mkkey(v1, r1, i2);
                if (nk < k1) k1 = nk;
            }
        }
        // row i2's exact new key from the fresh values (u32 trick)
        {
            unsigned lm = cb0 < cb1 ? cb0 : cb1;
            int lcol = (cb0 <= cb1) ? r0 : r1;
            unsigned gm = wave_umin_bcast(lm);
            unsigned long long mk2 = __ballot(lm == gm);
            int ls = __ffsll(mk2) - 1;
            int col = __builtin_amdgcn_readlane(lcol, ls);
            unsigned long long ki2 = ((unsigned long long)gm << 32) | (unsigned)((i2 << 7) | col);
            if (r0 == i2) k0 = ki2;
            if (r1 == i2) k1 = ki2;
        }

        // P6: dirty-row rescans (2 rows/round, b128 + alive-mask + u32 half-min)
        unsigned long long mm0 = m0, mm1 = m1;
        while (mm0 | mm1) {
            int rA, rB;
            bool hasB = false;
            if (mm0) { int t = __ffsll(mm0) - 1; rA = 2 * t; mm0 &= mm0 - 1; }
            else     { int t = __ffsll(mm1) - 1; rA = 2 * t + 1; mm1 &= mm1 - 1; }
            if (mm0) { int t = __ffsll(mm0) - 1; rB = 2 * t; mm0 &= mm0 - 1; hasB = true; }
            else if (mm1) { int t = __ffsll(mm1) - 1; rB = 2 * t + 1; mm1 &= mm1 - 1; hasB = true; }
            else rB = rA;

            int r = (lane < 32) ? rA : rB;
            int hh = lane & 31;
            float4 cv = *(const float4*)&cost[r * RSTR + 4 * hh];
            unsigned long long word = (hh < 16) ? alive0 : alive1;
            unsigned nib = (unsigned)(word >> ((4 * hh) & 63)) & 0xFu;
            unsigned b0_ = (nib & 1u) ? __float_as_uint(cv.x) : 0xFFFFFFFFu;
            unsigned b1_ = (nib & 2u) ? __float_as_uint(cv.y) : 0xFFFFFFFFu;
            unsigned b2_ = (nib & 4u) ? __float_as_uint(cv.z) : 0xFFFFFFFFu;
            unsigned b3_ = (nib & 8u) ? __float_as_uint(cv.w) : 0xFFFFFFFFu;
            unsigned m = b0_; int c = 0;
            if (b1_ < m) { m = b1_; c = 1; }
            if (b2_ < m) { m = b2_; c = 2; }
            if (b3_ < m) { m = b3_; c = 3; }
            int lcol = 4 * hh + c;
            unsigned hm = half_umin(m);
            unsigned vA = (unsigned)__builtin_amdgcn_readlane((int)hm, 31);
            unsigned vB = (unsigned)__builtin_amdgcn_readlane((int)hm, 63);
            unsigned vref = (lane < 32) ? vA : vB;
            unsigned long long msk = __ballot(m == vref);
            int laneA = __ffsll(msk & 0xFFFFFFFFull) - 1;
            int laneB = 32 + __ffsll(msk >> 32) - 1;
            int colA = __builtin_amdgcn_readlane(lcol, laneA);
            int colB = __builtin_amdgcn_readlane(lcol, laneB);
            unsigned long long keyA = ((unsigned long long)vA << 32) | (unsigned)((rA << 7) | colA);
            unsigned long long keyB = ((unsigned long long)vB << 32) | (unsigned)((rB << 7) | colB);
            if (lane == (rA >> 1)) { if (rA & 1) k1 = keyA; else k0 = keyA; }
            if (hasB && lane == (rB >> 1)) { if (rB & 1) k1 = keyB; else k0 = keyB; }
        }

        // prefetch next iteration's own-row centroids (overlaps next P1/P3)
#pragma unroll
        for (int d = 0; d < 32; ++d) pref[d] = *(const float2*)&centsT[d * CSTR + r0];
    }

    // final relabel
    szsE[r0] = s0;
    szsE[r1] = s1;
    __asm__ volatile("s_waitcnt lgkmcnt(0)" ::: "memory");
    if (lane == 0) {
        int c = 0;
        for (int i = 0; i < NPTS; ++i) rnk[i] = (szsE[i] > 0.f) ? c++ : -1;
    }
    __asm__ volatile("s_waitcnt lgkmcnt(0)" ::: "memory");
    out[b * NPTS + r0] = rnk[lab0];
    out[b * NPTS + r1] = rnk[lab1];
}

extern "C" void kernel_launch(void* const* d_in, const int* in_sizes, int n_in,
                              void* d_out, int out_size, void* d_ws, size_t ws_size,
                              hipStream_t stream) {
    const float* x  = (const float*)d_in[0];
    const float* W1 = (const float*)d_in[1];
    const float* b1 = (const float*)d_in[2];
    const float* W2 = (const float*)d_in[3];
    const float* b2 = (const float*)d_in[4];

    float* h = (float*)d_ws;
    float* feats = h + (size_t)MROWS * H1;
    int* out = (int*)d_out;

    mlp1_kernel<<<dim3(MROWS / 128, H1 / 64), 256, 0, stream>>>(x, W1, b1, h);
    mlp2_kernel<<<MROWS / 16, 256, 0, stream>>>(h, W2, b2, feats);
    ward_kernel<<<BB, 256, 0, stream>>>(feats, out);
}